// Round 4
// baseline (609.864 us; speedup 1.0000x reference)
//
#include <hip/hip_runtime.h>

#define N_NODES 16384
#define N_EDGES 262144
#define F_IN    128
#define DIM     64
#define N_CLS   40
#define KT      16
#define EPSF    1e-8f

__device__ __forceinline__ float rlane(float v, int k) {
    return __int_as_float(__builtin_amdgcn_readlane(__float_as_int(v), k));
}

// ---------------- degree count (int) ----------------
__global__ __launch_bounds__(256) void k_degree(const int* __restrict__ dst,
                                                int* __restrict__ deg) {
    int e = blockIdx.x * 256 + threadIdx.x;
    if (e < N_EDGES) atomicAdd(&deg[dst[e]], 1);
}

// ---------------- exclusive prefix scan over 16384 ints, one block; also zeroes Mm ----------------
__global__ __launch_bounds__(1024) void k_scan(const int* __restrict__ deg,
                                               int* __restrict__ base,
                                               int* __restrict__ offs,
                                               float* __restrict__ Mm) {
    for (int i = threadIdx.x; i < KT * (DIM + 1); i += 1024) Mm[i] = 0.f;

    const int tid = threadIdx.x, lane = tid & 63, w = tid >> 6;  // 16 waves
    int loc[16];
    int s = 0;
    const int b0 = tid * 16;
#pragma unroll
    for (int k = 0; k < 16; ++k) { loc[k] = s; s += deg[b0 + k]; }
    int v = s;
#pragma unroll
    for (int off = 1; off < 64; off <<= 1) {
        int t = __shfl_up(v, off);
        if (lane >= off) v += t;
    }
    __shared__ int wsum[16];
    if (lane == 63) wsum[w] = v;
    __syncthreads();
    if (w == 0 && lane < 16) {
        int x = wsum[lane];
#pragma unroll
        for (int off = 1; off < 16; off <<= 1) {
            int t = __shfl_up(x, off);
            if (lane >= off) x += t;
        }
        wsum[lane] = x;
    }
    __syncthreads();
    const int wbase = (w == 0) ? 0 : wsum[w - 1];
    const int excl  = wbase + v - s;
#pragma unroll
    for (int k = 0; k < 16; ++k) {
        int bb = excl + loc[k];
        base[b0 + k] = bb;
        offs[b0 + k] = bb;
    }
}

// ---------------- bucket edges by dst ----------------
__global__ __launch_bounds__(256) void k_bucket(const int* __restrict__ src,
                                                const int* __restrict__ dst,
                                                int* __restrict__ offs,
                                                int* __restrict__ ssrc) {
    int e = blockIdx.x * 256 + threadIdx.x;
    if (e < N_EDGES) {
        int pos = atomicAdd(&offs[dst[e]], 1);
        ssrc[pos] = src[e];
    }
}

// ---------------- dual projection: p = X@Wl, r = X@Wr ----------------
// 256 thr = 4 waves; wave owns 8 rows in registers, weights in LDS (2 ds/k),
// row elements broadcast via v_readlane (VALU pipe, no LDS).
template<int KDIM>
__global__ __launch_bounds__(256) void k_proj(const float* __restrict__ X,
                                              const float* __restrict__ Wl,
                                              const float* __restrict__ Wr,
                                              float* __restrict__ p,
                                              float* __restrict__ r) {
    __shared__ float sWl[KDIM * DIM];
    __shared__ float sWr[KDIM * DIM];
    const int tid = threadIdx.x, lane = tid & 63, w = tid >> 6;
    for (int i = tid; i < KDIM * DIM / 4; i += 256) {
        ((float4*)sWl)[i] = ((const float4*)Wl)[i];
        ((float4*)sWr)[i] = ((const float4*)Wr)[i];
    }
    __syncthreads();

    const int row0 = (blockIdx.x * 4 + w) * 8;
    float xa[8], xb[8];
#pragma unroll
    for (int j = 0; j < 8; ++j) {
        xa[j] = X[(size_t)(row0 + j) * KDIM + lane];
        if constexpr (KDIM == 128) xb[j] = X[(size_t)(row0 + j) * KDIM + 64 + lane];
    }
    float accl[8] = {0.f, 0.f, 0.f, 0.f, 0.f, 0.f, 0.f, 0.f};
    float accr[8] = {0.f, 0.f, 0.f, 0.f, 0.f, 0.f, 0.f, 0.f};
#pragma unroll 8
    for (int k = 0; k < 64; ++k) {
        const float wl = sWl[k * DIM + lane];
        const float wr = sWr[k * DIM + lane];
#pragma unroll
        for (int j = 0; j < 8; ++j) {
            const float xv = rlane(xa[j], k);
            accl[j] = fmaf(xv, wl, accl[j]);
            accr[j] = fmaf(xv, wr, accr[j]);
        }
    }
    if constexpr (KDIM == 128) {
#pragma unroll 8
        for (int k = 0; k < 64; ++k) {
            const float wl = sWl[(64 + k) * DIM + lane];
            const float wr = sWr[(64 + k) * DIM + lane];
#pragma unroll
            for (int j = 0; j < 8; ++j) {
                const float xv = rlane(xb[j], k);
                accl[j] = fmaf(xv, wl, accl[j]);
                accr[j] = fmaf(xv, wr, accr[j]);
            }
        }
    }
#pragma unroll
    for (int j = 0; j < 8; ++j) {
        p[(size_t)(row0 + j) * DIM + lane] = accl[j];
        r[(size_t)(row0 + j) * DIM + lane] = accr[j];
    }
}

// ---------------- gather layer1: h1 = relu(mean_j p[src_j] + b + r) ----------------
// One wave per block; node = blockIdx.x is provably uniform -> ssrc/base/deg
// loads scalarize to s_load, p-row loads are SGPR-base + lane.
__global__ __launch_bounds__(64) void k_gather1(const int* __restrict__ ssrc,
                                                const int* __restrict__ base,
                                                const int* __restrict__ deg,
                                                const float* __restrict__ p,
                                                const float* __restrict__ r,
                                                const float* __restrict__ b,
                                                float* __restrict__ h) {
    const int lane = threadIdx.x;
    const int node = blockIdx.x;
    const int s0 = base[node];
    const int d  = deg[node];
    float acc = 0.f;
    int t = 0;
    for (; t + 8 <= d; t += 8) {
        const int e0 = ssrc[s0 + t + 0], e1 = ssrc[s0 + t + 1];
        const int e2 = ssrc[s0 + t + 2], e3 = ssrc[s0 + t + 3];
        const int e4 = ssrc[s0 + t + 4], e5 = ssrc[s0 + t + 5];
        const int e6 = ssrc[s0 + t + 6], e7 = ssrc[s0 + t + 7];
        const float v0 = p[(size_t)e0 * DIM + lane], v1 = p[(size_t)e1 * DIM + lane];
        const float v2 = p[(size_t)e2 * DIM + lane], v3 = p[(size_t)e3 * DIM + lane];
        const float v4 = p[(size_t)e4 * DIM + lane], v5 = p[(size_t)e5 * DIM + lane];
        const float v6 = p[(size_t)e6 * DIM + lane], v7 = p[(size_t)e7 * DIM + lane];
        acc += ((v0 + v1) + (v2 + v3)) + ((v4 + v5) + (v6 + v7));
    }
    for (; t < d; ++t) acc += p[(size_t)ssrc[s0 + t] * DIM + lane];
    float val = acc / fmaxf((float)d, 1.f) + b[lane] + r[(size_t)node * DIM + lane];
    h[(size_t)node * DIM + lane] = fmaxf(val, 0.f);
}

// ---------------- gather layer2 + score + Taylor moments ----------------
__global__ __launch_bounds__(64) void k_gather2(const int* __restrict__ ssrc,
                                                const int* __restrict__ base,
                                                const int* __restrict__ deg,
                                                const float* __restrict__ p,
                                                const float* __restrict__ r,
                                                const float* __restrict__ b,
                                                const float* __restrict__ aux,
                                                float* __restrict__ h2,
                                                float* __restrict__ score,
                                                float* __restrict__ Mm) {
    const int lane = threadIdx.x;
    const float bb = b[lane];
    const float av = aux[lane];
    float an2 = av * av;
#pragma unroll
    for (int off = 32; off >= 1; off >>= 1) an2 += __shfl_xor(an2, off);
    const float anorm = fmaxf(sqrtf(an2), EPSF);

    float accM[KT], accm[KT];
#pragma unroll
    for (int k = 0; k < KT; ++k) { accM[k] = 0.f; accm[k] = 0.f; }

    for (int node = blockIdx.x; node < N_NODES; node += gridDim.x) {
        const int s0 = base[node];
        const int d  = deg[node];
        float acc = 0.f;
        int t = 0;
        for (; t + 8 <= d; t += 8) {
            const int e0 = ssrc[s0 + t + 0], e1 = ssrc[s0 + t + 1];
            const int e2 = ssrc[s0 + t + 2], e3 = ssrc[s0 + t + 3];
            const int e4 = ssrc[s0 + t + 4], e5 = ssrc[s0 + t + 5];
            const int e6 = ssrc[s0 + t + 6], e7 = ssrc[s0 + t + 7];
            const float v0 = p[(size_t)e0 * DIM + lane], v1 = p[(size_t)e1 * DIM + lane];
            const float v2 = p[(size_t)e2 * DIM + lane], v3 = p[(size_t)e3 * DIM + lane];
            const float v4 = p[(size_t)e4 * DIM + lane], v5 = p[(size_t)e5 * DIM + lane];
            const float v6 = p[(size_t)e6 * DIM + lane], v7 = p[(size_t)e7 * DIM + lane];
            acc += ((v0 + v1) + (v2 + v3)) + ((v4 + v5) + (v6 + v7));
        }
        for (; t < d; ++t) acc += p[(size_t)ssrc[s0 + t] * DIM + lane];

        const float hv = acc / fmaxf((float)d, 1.f) + bb + r[(size_t)node * DIM + lane];
        h2[(size_t)node * DIM + lane] = hv;

        float d1 = hv * av, d2 = hv * hv;
#pragma unroll
        for (int off = 32; off >= 1; off >>= 1) {
            d1 += __shfl_xor(d1, off);
            d2 += __shfl_xor(d2, off);
        }
        const float s = d1 / (anorm * fmaxf(sqrtf(d2), EPSF));
        if (lane == 0) score[node] = s;
        float tt = expf(-s * s);
#pragma unroll
        for (int k = 0; k < KT; ++k) {
            accM[k] = fmaf(tt, hv, accM[k]);
            accm[k] += tt;
            tt *= s;
        }
    }

#pragma unroll
    for (int k = 0; k < KT; ++k) atomicAdd(&Mm[k * DIM + lane], accM[k]);
    if (lane == 0) {
#pragma unroll
        for (int k = 0; k < KT; ++k) atomicAdd(&Mm[KT * DIM + k], accm[k]);
    }
}

// ---------------- fused z + classifier ----------------
__global__ __launch_bounds__(256) void k_zcls(const float* __restrict__ score,
                                              const float* __restrict__ Mm,
                                              const float* __restrict__ h,
                                              const float* __restrict__ Wc,
                                              const float* __restrict__ bc,
                                              float* __restrict__ out) {
    __shared__ float sM[KT * DIM];
    __shared__ float sm[KT];
    __shared__ float sW[2 * DIM * N_CLS];
    __shared__ float sb[N_CLS];
    __shared__ float sh[4][DIM];
    __shared__ float sz[4][DIM];
    const int tid = threadIdx.x;
    for (int idx = tid; idx < KT * DIM; idx += 256) sM[idx] = Mm[idx];
    if (tid < KT) sm[tid] = Mm[KT * DIM + tid];
    for (int idx = tid; idx < 2 * DIM * N_CLS; idx += 256) sW[idx] = Wc[idx];
    if (tid < N_CLS) sb[tid] = bc[tid];
    __syncthreads();

    const int lane = tid & 63, w = tid >> 6;
    const int gw = blockIdx.x * 4 + w, nw = gridDim.x * 4;
    for (int i = gw; i < N_NODES; i += nw) {
        const float s2 = 2.f * score[i];
        float c = 1.f, num = 0.f, den = 0.f;
#pragma unroll
        for (int k = 0; k < KT; ++k) {
            num = fmaf(c, sM[k * DIM + lane], num);
            den = fmaf(c, sm[k], den);
            c *= s2 * (1.0f / (float)(k + 1));
        }
        sz[w][lane] = num / den;
        sh[w][lane] = h[(size_t)i * DIM + lane];
        if (lane < N_CLS) {
            float acc = sb[lane];
#pragma unroll 8
            for (int k = 0; k < DIM; ++k)
                acc = fmaf(sh[w][k], sW[k * N_CLS + lane], acc);
#pragma unroll 8
            for (int k = 0; k < DIM; ++k)
                acc = fmaf(sz[w][k], sW[(DIM + k) * N_CLS + lane], acc);
            out[(size_t)i * N_CLS + lane] = acc;
        }
    }
}

extern "C" void kernel_launch(void* const* d_in, const int* in_sizes, int n_in,
                              void* d_out, int out_size, void* d_ws, size_t ws_size,
                              hipStream_t stream) {
    const float* x   = (const float*)d_in[0];
    const int*   ei  = (const int*)d_in[1];
    const float* W1l = (const float*)d_in[2];
    const float* b1  = (const float*)d_in[3];
    const float* W1r = (const float*)d_in[4];
    const float* W2l = (const float*)d_in[5];
    const float* b2  = (const float*)d_in[6];
    const float* W2r = (const float*)d_in[7];
    const float* aux = (const float*)d_in[8];
    const float* Wc  = (const float*)d_in[9];
    const float* bc  = (const float*)d_in[10];
    float*       out = (float*)d_out;

    const int* src = ei;
    const int* dst = ei + N_EDGES;

    float*       W  = (float*)d_ws;
    const size_t ND = (size_t)N_NODES * DIM;
    float* pp    = W;
    float* rr    = W + ND;
    float* h1    = W + 2 * ND;
    float* hh    = W + 3 * ND;
    float* score = W + 4 * ND;
    int*   deg   = (int*)(score + N_NODES);
    float* Mm    = (float*)(deg + N_NODES);
    int*   base  = (int*)(Mm + KT * (DIM + 1));
    int*   offs  = base + N_NODES;
    int*   ssrc  = offs + N_NODES;

    hipMemsetAsync(deg, 0, N_NODES * sizeof(int), stream);
    k_degree<<<N_EDGES / 256, 256, 0, stream>>>(dst, deg);
    k_scan<<<1, 1024, 0, stream>>>(deg, base, offs, Mm);
    k_bucket<<<N_EDGES / 256, 256, 0, stream>>>(src, dst, offs, ssrc);

    k_proj<F_IN><<<512, 256, 0, stream>>>(x, W1l, W1r, pp, rr);
    k_gather1<<<N_NODES, 64, 0, stream>>>(ssrc, base, deg, pp, rr, b1, h1);

    k_proj<DIM><<<512, 256, 0, stream>>>(h1, W2l, W2r, pp, rr);
    k_gather2<<<2048, 64, 0, stream>>>(ssrc, base, deg, pp, rr, b2, aux, hh, score, Mm);

    k_zcls<<<512, 256, 0, stream>>>(score, Mm, hh, Wc, bc, out);
}